// Round 7
// baseline (151.623 us; speedup 1.0000x reference)
//
#include <hip/hip_runtime.h>
#include <hip/hip_bf16.h>

#define BATCH   2048
#define NFIELDS 32
#define EMBED   64
#define NPAIRS  496

typedef __attribute__((ext_vector_type(8))) short bf16x8;
typedef __attribute__((ext_vector_type(4))) float f32x4;

__device__ __forceinline__ unsigned short f2bf(float x) {
    unsigned int u = __float_as_uint(x);
    unsigned int r = 0x7fffu + ((u >> 16) & 1u);
    return (unsigned short)((u + r) >> 16);
}
__device__ __forceinline__ bf16x8 cvt8(const float* p) {
    float4 v0 = *(const float4*)p;
    float4 v1 = *(const float4*)(p + 4);
    bf16x8 o;
    o[0]=(short)f2bf(v0.x); o[1]=(short)f2bf(v0.y); o[2]=(short)f2bf(v0.z); o[3]=(short)f2bf(v0.w);
    o[4]=(short)f2bf(v1.x); o[5]=(short)f2bf(v1.y); o[6]=(short)f2bf(v1.z); o[7]=(short)f2bf(v1.w);
    return o;
}

// Single fused kernel. Block = (4-pair chunk, 64-batch tile). 4 waves; wave w owns
// pair chunk*4+w across the tile's 64 batches (4 sub-tiles of 16).
// MFMA computes D[m=i][n=batch] = sum_j K_p[i,j] * emb[b, r, j]; A = K rows
// (cvt fp32->bf16 on the fly, held in regs), B = emb_r rows (cvt on the fly, no LDS,
// no barriers in the loop). q stays fp32 from original emb (precision).
// XCD-pinned swizzle: batch-tiles of a chunk land on one XCD -> that XCD's ~62
// pairs of K (~2 MB fp32) are L2-resident, fetched from HBM once.
__global__ __launch_bounds__(256) void opn_fused(
    const float* __restrict__ emb, const float* __restrict__ kern,
    float* __restrict__ out)
{
    // bijective XCD-pinning swizzle: 3968 = 8 * 496
    const int bid = blockIdx.x;
    const int swz = (bid & 7) * 496 + (bid >> 3);
    const int chunk = swz >> 5;            // 0..123  (4-pair chunk)
    const int bt    = swz & 31;            // 0..31   (64-batch tile)

    const int tid  = threadIdx.x;
    const int wave = tid >> 6, lane = tid & 63;
    const int col  = lane & 15, quad = lane >> 4;
    const int pair = chunk * 4 + wave;

    // decode pair -> (r, c), triu k=1 row-major
    int r = 0, s = 0;
    while (pair >= s + (NFIELDS - 1 - r)) { s += NFIELDS - 1 - r; ++r; }
    const int c = r + 1 + (pair - s);

    __shared__ __align__(16) float Otile[64][4];

    // ---- A fragments: lane holds K_p[i = nt*16+col][j = ks*32 + quad*8 + t] ----
    // fp32 source: kern[i][pair][j] at i*(NPAIRS*EMBED) + pair*EMBED + j
    bf16x8 kfr[4][2];
    #pragma unroll
    for (int nt = 0; nt < 4; ++nt)
        #pragma unroll
        for (int ks = 0; ks < 2; ++ks)
            kfr[nt][ks] = cvt8(kern + (size_t)(nt*16 + col) * (NPAIRS*EMBED)
                                 + (size_t)pair * EMBED + ks*32 + quad*8);

    #pragma unroll
    for (int it = 0; it < 4; ++it) {
        const int brow = bt * 64 + it * 16 + col;

        // B fragments: emb[brow, r, j] cvt'd on the fly, j = ks*32 + quad*8 + t
        const float* ef = emb + ((size_t)brow * NFIELDS + r) * EMBED;
        bf16x8 bfr0 = cvt8(ef + quad*8);
        bf16x8 bfr1 = cvt8(ef + 32 + quad*8);

        // q: fp32 direct; lane needs q[brow][nt*16 + quad*4 .. +4]
        const float* qp = emb + ((size_t)brow * NFIELDS + c) * EMBED + quad*4;
        f32x4 q0 = *(const f32x4*)(qp);
        f32x4 q1 = *(const f32x4*)(qp + 16);
        f32x4 q2 = *(const f32x4*)(qp + 32);
        f32x4 q3 = *(const f32x4*)(qp + 48);

        float partial = 0.f;
        #pragma unroll
        for (int nt = 0; nt < 4; ++nt) {
            f32x4 acc = {0.f, 0.f, 0.f, 0.f};
            acc = __builtin_amdgcn_mfma_f32_16x16x32_bf16(kfr[nt][0], bfr0, acc, 0, 0, 0);
            acc = __builtin_amdgcn_mfma_f32_16x16x32_bf16(kfr[nt][1], bfr1, acc, 0, 0, 0);
            f32x4 qq = (nt == 0) ? q0 : (nt == 1) ? q1 : (nt == 2) ? q2 : q3;
            partial += acc[0]*qq[0] + acc[1]*qq[1] + acc[2]*qq[2] + acc[3]*qq[3];
        }
        // reduce over i: lanes {col, col+16, col+32, col+48}
        partial += __shfl_xor(partial, 16, 64);
        partial += __shfl_xor(partial, 32, 64);
        if (quad == 0) Otile[it*16 + col][wave] = partial;
    }
    __syncthreads();

    if (tid < 64) {
        f32x4 o = *(const f32x4*)&Otile[tid][0];
        *(f32x4*)&out[((size_t)(bt*64 + tid)) * NPAIRS + chunk*4] = o;
    }
}

extern "C" void kernel_launch(void* const* d_in, const int* in_sizes, int n_in,
                              void* d_out, int out_size, void* d_ws, size_t ws_size,
                              hipStream_t stream) {
    const float* emb  = (const float*)d_in[0];   // (2048, 32, 64) fp32
    const float* kern = (const float*)d_in[1];   // (64, 496, 64) fp32
    float* out = (float*)d_out;                  // (2048, 1, 496) fp32

    // grid: 124 chunks * 32 batch-tiles = 3968 blocks (1D, swizzled in-kernel)
    opn_fused<<<dim3(3968), 256, 0, stream>>>(emb, kern, out);
}

// Round 8
// 129.698 us; speedup vs baseline: 1.1690x; 1.1690x over previous
//
#include <hip/hip_runtime.h>
#include <hip/hip_bf16.h>

#define BATCH   2048
#define NFIELDS 32
#define EMBED   64
#define NPAIRS  496

typedef __attribute__((ext_vector_type(8))) short bf16x8;
typedef __attribute__((ext_vector_type(4))) float f32x4;

__device__ __forceinline__ unsigned short f2bf(float x) {
    unsigned int u = __float_as_uint(x);
    unsigned int r = 0x7fffu + ((u >> 16) & 1u);
    return (unsigned short)((u + r) >> 16);
}
__device__ __forceinline__ float bf2f(unsigned short b) {
    return __uint_as_float(((unsigned int)b) << 16);
}
__device__ __forceinline__ bf16x8 cvt8(const float* p) {
    float4 v0 = *(const float4*)p;
    float4 v1 = *(const float4*)(p + 4);
    bf16x8 o;
    o[0]=(short)f2bf(v0.x); o[1]=(short)f2bf(v0.y); o[2]=(short)f2bf(v0.z); o[3]=(short)f2bf(v0.w);
    o[4]=(short)f2bf(v1.x); o[5]=(short)f2bf(v1.y); o[6]=(short)f2bf(v1.z); o[7]=(short)f2bf(v1.w);
    return o;
}

// Prepass: emb fp32 -> bf16 (same layout); kernel fp32 [i][p][j] -> bf16 [p][i][j]
__global__ __launch_bounds__(256) void convert_prepass(
    const float* __restrict__ emb, const float* __restrict__ kern,
    unsigned short* __restrict__ embB, unsigned short* __restrict__ kernB)
{
    const int EMB4 = BATCH * NFIELDS * EMBED / 4;   // 1048576
    const int KER4 = EMBED * NPAIRS * EMBED / 4;    // 507904
    int t = blockIdx.x * blockDim.x + threadIdx.x;
    if (t < EMB4) {
        float4 v = ((const float4*)emb)[t];
        ushort4 o;
        o.x = f2bf(v.x); o.y = f2bf(v.y); o.z = f2bf(v.z); o.w = f2bf(v.w);
        *(ushort4*)(embB + (size_t)t * 4) = o;
    } else if (t < EMB4 + KER4) {
        int u = t - EMB4;
        int j4   = u & 15;
        int rest = u >> 4;
        int p = rest % NPAIRS;
        int i = rest / NPAIRS;
        float4 v = *(const float4*)(kern + (size_t)i * (NPAIRS*EMBED) + (size_t)p * EMBED + j4*4);
        ushort4 o;
        o.x = f2bf(v.x); o.y = f2bf(v.y); o.z = f2bf(v.z); o.w = f2bf(v.w);
        *(ushort4*)(kernB + (size_t)p * 4096 + i * 64 + j4 * 4) = o;
    }
}

// Main: block = (4-pair chunk, 64-batch tile). 4 waves; wave w owns pair chunk*4+w.
// MFMA computes D[m=i][n=batch] = sum_j K_p[i,j] * emb[b, r, j]; A = K rows in regs,
// B = emb_r rows direct from global (bf16, no LDS, no barriers in loop).
// q also bf16 (halves the dominant c-side HBM stream vs fp32).
// XCD-pinned swizzle (3968 = 8*496, bijective): each XCD's ~1 MB K slice stays
// L2-resident; emb c-side streams.
template<bool PRE>
__global__ __launch_bounds__(256) void opn_fused(
    const void* __restrict__ embP, const void* __restrict__ kernP,
    const float* __restrict__ embF, float* __restrict__ out)
{
    const int bid = blockIdx.x;
    const int swz = (bid & 7) * 496 + (bid >> 3);
    const int chunk = swz >> 5;            // 0..123  (4-pair chunk)
    const int bt    = swz & 31;            // 0..31   (64-batch tile)

    const int tid  = threadIdx.x;
    const int wave = tid >> 6, lane = tid & 63;
    const int col  = lane & 15, quad = lane >> 4;
    const int pair = chunk * 4 + wave;

    // decode pair -> (r, c), triu k=1 row-major
    int r = 0, s = 0;
    while (pair >= s + (NFIELDS - 1 - r)) { s += NFIELDS - 1 - r; ++r; }
    const int c = r + 1 + (pair - s);

    __shared__ __align__(16) float Otile[64][4];

    // ---- A fragments: lane holds K_p[i = nt*16+col][j = ks*32 + quad*8 + t] ----
    bf16x8 kfr[4][2];
    if (PRE) {
        const unsigned short* kb = (const unsigned short*)kernP + (size_t)pair * 4096;
        #pragma unroll
        for (int nt = 0; nt < 4; ++nt)
            #pragma unroll
            for (int ks = 0; ks < 2; ++ks)
                kfr[nt][ks] = *(const bf16x8*)(kb + (nt*16 + col) * 64 + ks*32 + quad*8);
    } else {
        const float* kf = (const float*)kernP;
        #pragma unroll
        for (int nt = 0; nt < 4; ++nt)
            #pragma unroll
            for (int ks = 0; ks < 2; ++ks)
                kfr[nt][ks] = cvt8(kf + (size_t)(nt*16 + col) * (NPAIRS*EMBED)
                                     + (size_t)pair * EMBED + ks*32 + quad*8);
    }

    #pragma unroll
    for (int it = 0; it < 4; ++it) {
        const int brow = bt * 64 + it * 16 + col;

        bf16x8 bfr0, bfr1;
        float qf[4][4];
        if (PRE) {
            const unsigned short* eb = (const unsigned short*)embP
                                     + ((size_t)brow * NFIELDS + r) * EMBED;
            bfr0 = *(const bf16x8*)(eb + quad*8);
            bfr1 = *(const bf16x8*)(eb + 32 + quad*8);
            // q bf16: lane needs q[brow][c][nt*16 + quad*4 .. +4]
            const unsigned short* qb = (const unsigned short*)embP
                                     + ((size_t)brow * NFIELDS + c) * EMBED + quad*4;
            #pragma unroll
            for (int nt = 0; nt < 4; ++nt) {
                ushort4 qv = *(const ushort4*)(qb + nt*16);
                qf[nt][0] = bf2f(qv.x); qf[nt][1] = bf2f(qv.y);
                qf[nt][2] = bf2f(qv.z); qf[nt][3] = bf2f(qv.w);
            }
        } else {
            const float* ef = (const float*)embP + ((size_t)brow * NFIELDS + r) * EMBED;
            bfr0 = cvt8(ef + quad*8);
            bfr1 = cvt8(ef + 32 + quad*8);
            const float* qp = embF + ((size_t)brow * NFIELDS + c) * EMBED + quad*4;
            #pragma unroll
            for (int nt = 0; nt < 4; ++nt) {
                f32x4 qv = *(const f32x4*)(qp + nt*16);
                qf[nt][0] = qv[0]; qf[nt][1] = qv[1]; qf[nt][2] = qv[2]; qf[nt][3] = qv[3];
            }
        }

        float partial = 0.f;
        #pragma unroll
        for (int nt = 0; nt < 4; ++nt) {
            f32x4 acc = {0.f, 0.f, 0.f, 0.f};
            acc = __builtin_amdgcn_mfma_f32_16x16x32_bf16(kfr[nt][0], bfr0, acc, 0, 0, 0);
            acc = __builtin_amdgcn_mfma_f32_16x16x32_bf16(kfr[nt][1], bfr1, acc, 0, 0, 0);
            partial += acc[0]*qf[nt][0] + acc[1]*qf[nt][1] + acc[2]*qf[nt][2] + acc[3]*qf[nt][3];
        }
        // reduce over i: lanes {col, col+16, col+32, col+48}
        partial += __shfl_xor(partial, 16, 64);
        partial += __shfl_xor(partial, 32, 64);
        if (quad == 0) Otile[it*16 + col][wave] = partial;
    }
    __syncthreads();

    if (tid < 64) {
        f32x4 o = *(const f32x4*)&Otile[tid][0];
        *(f32x4*)&out[((size_t)(bt*64 + tid)) * NPAIRS + chunk*4] = o;
    }
}

extern "C" void kernel_launch(void* const* d_in, const int* in_sizes, int n_in,
                              void* d_out, int out_size, void* d_ws, size_t ws_size,
                              hipStream_t stream) {
    const float* emb  = (const float*)d_in[0];   // (2048, 32, 64) fp32
    const float* kern = (const float*)d_in[1];   // (64, 496, 64) fp32
    float* out = (float*)d_out;                  // (2048, 1, 496) fp32

    const size_t embElems  = (size_t)BATCH * NFIELDS * EMBED;   // 4194304
    const size_t kernElems = (size_t)EMBED * NPAIRS * EMBED;    // 2031616
    const size_t need = (embElems + kernElems) * sizeof(unsigned short);

    if (ws_size >= need) {
        unsigned short* embB  = (unsigned short*)d_ws;
        unsigned short* kernB = embB + embElems;
        int total4 = (int)((embElems + kernElems) / 4);         // 1556480
        convert_prepass<<<(total4 + 255) / 256, 256, 0, stream>>>(emb, kern, embB, kernB);
        opn_fused<true><<<dim3(3968), 256, 0, stream>>>(
            (const void*)embB, (const void*)kernB, emb, out);
    } else {
        opn_fused<false><<<dim3(3968), 256, 0, stream>>>(
            (const void*)emb, (const void*)kern, emb, out);
    }
}